// Round 8
// baseline (158.128 us; speedup 1.0000x reference)
//
#include <hip/hip_runtime.h>
#include <math.h>

#define N_S 32
#define C_DIM 3
#define F_DIM 3277
#define T_DIM 256
#define FT (F_DIM * T_DIM)          /* 838912  */
#define CFT (F_DIM * T_DIM * C_DIM) /* 2516736 */
#define CFT4 (CFT / 4)              /* 629184 float4 per sample */
#define FC_IDX 1084
#define N_NOISE 2949
#define NQ (3 * N_NOISE * 64)       /* 566208 noise float4s per sample */
#define TH0 104832                  /* 1638*64 */
#define TH1 293568                  /* TH0 + 188736 */
#define TH2 482304                  /* TH0 + 2*188736 */
#define SKIP4 20992                 /* 328*64 */
#define NB 64                       /* noise blocks per sample */
#define NPART NB
#define STRIDE4 (NB * 256)          /* 16384 */
#define TOTAL4 ((N_S * CFT) / 4)    /* 20,133,888 */
#define NFILL 2048                  /* fill blocks */
#define WPB (TOTAL4 / NFILL)        /* 9831 float4 per fill block (exact) */

typedef float f4 __attribute__((ext_vector_type(4)));

struct WS {
  float              noise_partial[N_S][256];
  int                mid[N_S];
  int                hb[N_S];
  unsigned long long tbits[N_S][4];
};

// ---- K1: fused — even blocks: R7 noise read (NT+MLP, verbatim numerics);
//                  odd  blocks: contiguous zero-fill of d_out ----------------
__global__ __launch_bounds__(256) void k_main(const f4* __restrict__ xv,
                                              float4* __restrict__ ov,
                                              WS* __restrict__ ws) {
  int bx = blockIdx.x;
  int t  = threadIdx.x;

  if (bx & 1) {
    // ---------------- zero-fill path: contiguous, fill-clone ----------------
    int fb = bx >> 1;
    float4* wbase = ov + (size_t)fb * WPB;
    const float4 z = {0.f, 0.f, 0.f, 0.f};
    for (int j = t; j < WPB; j += 256) wbase[j] = z;
    return;
  }

  // ---------------- noise path: VERBATIM R7 (passed) -------------------------
  int nb = bx >> 1;                 // 0..2047
  int n  = nb >> 6;                 // sample
  int b  = nb & 63;                 // comb block within sample
  const f4* smp = xv + (size_t)n * CFT4;
  int q0 = b * 256 + t;
  float a0 = 0.f, a1 = 0.f, a2 = 0.f, a3 = 0.f;

#define LOADACC(J, ACC)                                                        \
  {                                                                            \
    int it = i + (J);                                                          \
    int q  = q0 + it * STRIDE4;                                                \
    if (it < 35 && q < NQ) {                                                   \
      int add = (q >= TH0) * SKIP4 + (q >= TH1) * SKIP4 + (q >= TH2) * SKIP4;  \
      f4 v = __builtin_nontemporal_load(smp + q + add);                        \
      ACC += fabsf(v.x) + fabsf(v.y) + fabsf(v.z) + fabsf(v.w);                \
    }                                                                          \
  }

  #pragma unroll
  for (int i = 0; i < 36; i += 4) {
    LOADACC(0, a0)
    LOADACC(1, a1)
    LOADACC(2, a2)
    LOADACC(3, a3)
  }
#undef LOADACC

  float acc = (a0 + a1) + (a2 + a3);
  for (int off = 32; off; off >>= 1) acc += __shfl_down(acc, off);
  __shared__ double wsum[4];
  int w = t >> 6, lane = t & 63;
  if (lane == 0) wsum[w] = (double)acc;
  __syncthreads();
  if (t == 0) {
    ws->noise_partial[n][b] = (float)(wsum[0] + wsum[1] + wsum[2] + wsum[3]);
  }
}

// ---- K2: per-sample stats — VERBATIM from rounds 5-7 (passed) ---------------
__global__ __launch_bounds__(256) void k_stats(const float* __restrict__ x,
                                               WS* __restrict__ ws) {
  int n = blockIdx.x;
  int t = threadIdx.x;
  const float* p = x + (size_t)n * CFT + (size_t)FC_IDX * T_DIM + t;
  float m = fabsf(p[0]) + fabsf(p[FT]) + fabsf(p[2 * FT]);

  __shared__ float  smag[256];
  __shared__ float  sv[256];
  __shared__ int    si[256];
  __shared__ double sd[256];
  smag[t] = m; sv[t] = m; si[t] = t;
  sd[t] = (t < NPART) ? (double)ws->noise_partial[n][t] : 0.0;
  __syncthreads();
  for (int s = 128; s > 0; s >>= 1) {
    if (t < s) {
      if (sv[t + s] > sv[t] || (sv[t + s] == sv[t] && si[t + s] < si[t])) {
        sv[t] = sv[t + s]; si[t] = si[t + s];
      }
      sd[t] += sd[t + s];
    }
    __syncthreads();
  }
  if (t == 0) {
    int mid = si[0];
    double noise_d = sd[0] / ((double)N_NOISE * (double)T_DIM);
    int lo = mid - 8; if (lo < 0) lo = 0;
    int hi = mid + 8; if (hi > T_DIM) hi = T_DIM;
    double sig_d = 0.0;
    for (int tt = lo; tt < hi; ++tt) sig_d += (double)smag[tt];
    float sig = (float)sig_d, noise = (float)noise_d;
    float d   = sig - noise;
    float snr = 10.0f * log10f((d * d) / (noise * noise));
    float hbf = 12.5f * (snr - 20.0f) + 27.0f;
    int hb = (int)truncf(hbf);
    if (hb < 8) hb = 8;
    ws->mid[n] = mid;
    ws->hb[n]  = hb;
    int wlo = mid - 8, whi = mid + 8;
    #pragma unroll
    for (int wd = 0; wd < 4; ++wd) {
      int base = wd * 64;
      int a = wlo - base; if (a < 0) a = 0;
      int bq = whi - base; if (bq > 64) bq = 64;
      unsigned long long msk = 0ULL;
      if (bq > a) {
        unsigned long long hiM = (bq >= 64) ? ~0ULL : ((1ULL << bq) - 1ULL);
        unsigned long long loM = (1ULL << a) - 1ULL;
        msk = hiM & ~loM;
      }
      ws->tbits[n][wd] = msk;
    }
  }
}

// ---- K3: band rewrite — VERBATIM from rounds 2/3/6 (passed) -----------------
__global__ __launch_bounds__(256) void k_band(const float* __restrict__ x,
                                              float* __restrict__ out,
                                              const WS* __restrict__ ws) {
  __shared__ unsigned long long um[4];
  int f = blockIdx.x;
  int t = threadIdx.x;
  if (t < 4) {
    unsigned long long m = 0ULL;
    #pragma unroll 4
    for (int n = 0; n < N_S; ++n) {
      int hb = ws->hb[n];
      if (f >= FC_IDX - hb && f < FC_IDX + hb) m |= ws->tbits[n][t];
    }
    um[t] = m;
  }
  __syncthreads();
  if ((um[0] | um[1] | um[2] | um[3]) == 0ULL) return;  // row outside all bands

  bool keep = (um[t >> 6] >> (t & 63)) & 1ULL;
  const float* xr   = x   + (size_t)f * T_DIM + t;
  float*       orow = out + (size_t)f * T_DIM + t;
  #pragma unroll 4
  for (int nc = 0; nc < N_S * C_DIM; ++nc) {
    size_t off = (size_t)nc * FT;
    float v = keep ? xr[off] : 0.f;
    orow[off] = v;
  }
}

extern "C" void kernel_launch(void* const* d_in, const int* in_sizes, int n_in,
                              void* d_out, int out_size, void* d_ws, size_t ws_size,
                              hipStream_t stream) {
  const float* x   = (const float*)d_in[0];
  float*       out = (float*)d_out;
  WS*          ws  = (WS*)d_ws;

  k_main <<<4096, 256, 0, stream>>>((const f4*)x, (float4*)out, ws);
  k_stats<<<N_S, 256, 0, stream>>>(x, ws);
  k_band <<<F_DIM, 256, 0, stream>>>(x, out, ws);
}